// Round 1
// baseline (540.459 us; speedup 1.0000x reference)
//
#include <hip/hip_runtime.h>
#include <math.h>

#define N_NODES 50000
#define N_EDGES 800000
#define IN_F 256
#define OUT_F 128
#define RANK 64

// ---------------- degrees ----------------
__global__ __launch_bounds__(256) void k_degrees(const int* __restrict__ src,
                                                 const int* __restrict__ dst,
                                                 int* __restrict__ out_deg,
                                                 int* __restrict__ in_deg) {
    int i = blockIdx.x * blockDim.x + threadIdx.x;
    if (i < N_EDGES) {
        atomicAdd(&out_deg[src[i]], 1);
        atomicAdd(&in_deg[dst[i]], 1);
    }
}

// ---------------- exclusive scan of in_deg -> row_start (+cursor copy) -----
__global__ __launch_bounds__(1024) void k_scan(const int* __restrict__ in_deg,
                                               int* __restrict__ row_start,
                                               int* __restrict__ cursor) {
    __shared__ int sums[1024];
    const int T = 1024;
    const int per = (N_NODES + T - 1) / T;  // 49
    int tid = threadIdx.x;
    int base = tid * per;

    int local = 0;
    for (int j = 0; j < per; ++j) {
        int idx = base + j;
        if (idx < N_NODES) local += in_deg[idx];
    }
    sums[tid] = local;
    __syncthreads();
    // Hillis-Steele inclusive scan
    for (int s = 1; s < T; s <<= 1) {
        int v = 0;
        if (tid >= s) v = sums[tid - s];
        __syncthreads();
        if (tid >= s) sums[tid] += v;
        __syncthreads();
    }
    int excl = sums[tid] - local;
    int run = excl;
    for (int j = 0; j < per; ++j) {
        int idx = base + j;
        if (idx < N_NODES) {
            int v = in_deg[idx];
            row_start[idx] = run;
            cursor[idx] = run;
            run += v;
        }
    }
    if (tid == T - 1) row_start[N_NODES] = sums[T - 1];
}

// ---------------- CSR fill ----------------
__global__ __launch_bounds__(256) void k_fill(const int* __restrict__ src,
                                              const int* __restrict__ dst,
                                              int* __restrict__ cursor,
                                              int* __restrict__ csr_src) {
    int i = blockIdx.x * blockDim.x + threadIdx.x;
    if (i < N_EDGES) {
        int p = atomicAdd(&cursor[dst[i]], 1);
        csr_src[p] = src[i];
    }
}

// ---------------- per-node GEMMs: feat_sum = feat_src@w1, feat_prod = tanh([feat_src,1]@w2)
#define NPB 4
__global__ __launch_bounds__(192) void k_gemm(const float* __restrict__ feat,
                                              const float* __restrict__ w1,
                                              const float* __restrict__ w2,
                                              const int* __restrict__ out_deg,
                                              float* __restrict__ feat_sum,
                                              float* __restrict__ feat_prod) {
    __shared__ float f[NPB][IN_F];
    __shared__ float scs[NPB];
    int n0 = blockIdx.x * NPB;
    int tid = threadIdx.x;

    if (tid < NPB) {
        int n = n0 + tid;
        float deg = (n < N_NODES) ? (float)out_deg[n] : 1.f;
        scs[tid] = rsqrtf(fmaxf(deg, 1.f));
    }
    __syncthreads();

    for (int idx = tid; idx < NPB * IN_F; idx += 192) {
        int i = idx >> 8;        // node within block
        int k = idx & (IN_F - 1);
        int n = n0 + i;
        float val = (n < N_NODES) ? feat[(size_t)n * IN_F + k] : 0.f;
        f[i][k] = val * scs[i];
    }
    __syncthreads();

    if (tid < OUT_F) {
        int j = tid;
        float acc[NPB] = {0.f, 0.f, 0.f, 0.f};
#pragma unroll 4
        for (int k = 0; k < IN_F; ++k) {
            float w = w1[k * OUT_F + j];
#pragma unroll
            for (int i = 0; i < NPB; ++i) acc[i] += f[i][k] * w;
        }
#pragma unroll
        for (int i = 0; i < NPB; ++i) {
            int n = n0 + i;
            if (n < N_NODES) feat_sum[(size_t)n * OUT_F + j] = acc[i];
        }
    } else {
        int r = tid - OUT_F;  // 0..63
        float acc[NPB] = {0.f, 0.f, 0.f, 0.f};
#pragma unroll 4
        for (int k = 0; k < IN_F; ++k) {
            float w = w2[k * RANK + r];
#pragma unroll
            for (int i = 0; i < NPB; ++i) acc[i] += f[i][k] * w;
        }
        float b = w2[IN_F * RANK + r];
#pragma unroll
        for (int i = 0; i < NPB; ++i) {
            int n = n0 + i;
            if (n < N_NODES) feat_prod[(size_t)n * RANK + r] = tanhf(acc[i] + b);
        }
    }
}

// ---------------- aggregation: one wave per dst node ----------------
__global__ __launch_bounds__(256) void k_agg(const float* __restrict__ feat_sum,
                                             const float* __restrict__ feat_prod,
                                             const int* __restrict__ row_start,
                                             const int* __restrict__ csr_src,
                                             const int* __restrict__ in_deg,
                                             const float* __restrict__ vmat,
                                             float* __restrict__ out) {
    __shared__ float prod_s[4][RANK];
    int wid = threadIdx.x >> 6;
    int lane = threadIdx.x & 63;
    int d = blockIdx.x * 4 + wid;   // grid sized exactly: d < N_NODES always

    int beg = row_start[d];
    int end = row_start[d + 1];

    float s0 = 0.f, s1 = 0.f;
    float pr = 1.f;
    for (int e = beg; e < end; ++e) {
        int s = csr_src[e];
        float2 f2 = *(const float2*)(feat_sum + (size_t)s * OUT_F + lane * 2);
        s0 += f2.x;
        s1 += f2.y;
        pr *= feat_prod[(size_t)s * RANK + lane];
    }
    prod_s[wid][lane] = pr;
    __syncthreads();

    float o0 = s0, o1 = s1;
    if (end > beg) {
#pragma unroll 8
        for (int r = 0; r < RANK; ++r) {
            float p = prod_s[wid][r];
            float2 v2 = *(const float2*)(vmat + r * OUT_F + lane * 2);
            o0 += p * v2.x;
            o1 += p * v2.y;
        }
    }
    float sc = rsqrtf(fmaxf((float)in_deg[d], 1.f));
    float2 res;
    res.x = o0 * sc;
    res.y = o1 * sc;
    *(float2*)(out + (size_t)d * OUT_F + lane * 2) = res;
}

extern "C" void kernel_launch(void* const* d_in, const int* in_sizes, int n_in,
                              void* d_out, int out_size, void* d_ws, size_t ws_size,
                              hipStream_t stream) {
    const float* feat = (const float*)d_in[0];
    const float* w1   = (const float*)d_in[1];
    const float* w2   = (const float*)d_in[2];
    const float* vmat = (const float*)d_in[3];
    const int*   src  = (const int*)d_in[4];
    const int*   dst  = (const int*)d_in[5];
    float* out = (float*)d_out;

    char* ws = (char*)d_ws;
    size_t off = 0;
    auto alloc = [&](size_t bytes) {
        void* p = ws + off;
        off = (off + bytes + 255) & ~(size_t)255;
        return p;
    };
    int* out_deg   = (int*)alloc(N_NODES * sizeof(int));
    int* in_deg    = (int*)alloc(N_NODES * sizeof(int));
    int* row_start = (int*)alloc((N_NODES + 1) * sizeof(int));
    int* cursor    = (int*)alloc(N_NODES * sizeof(int));
    int* csr_src   = (int*)alloc(N_EDGES * sizeof(int));
    float* feat_sum  = (float*)alloc((size_t)N_NODES * OUT_F * sizeof(float));
    float* feat_prod = (float*)alloc((size_t)N_NODES * RANK * sizeof(float));

    hipMemsetAsync(out_deg, 0, N_NODES * sizeof(int), stream);
    hipMemsetAsync(in_deg, 0, N_NODES * sizeof(int), stream);

    k_degrees<<<(N_EDGES + 255) / 256, 256, 0, stream>>>(src, dst, out_deg, in_deg);
    k_scan<<<1, 1024, 0, stream>>>(in_deg, row_start, cursor);
    k_fill<<<(N_EDGES + 255) / 256, 256, 0, stream>>>(src, dst, cursor, csr_src);
    k_gemm<<<(N_NODES + NPB - 1) / NPB, 192, 0, stream>>>(feat, w1, w2, out_deg,
                                                          feat_sum, feat_prod);
    k_agg<<<N_NODES / 4, 256, 0, stream>>>(feat_sum, feat_prod, row_start, csr_src,
                                           in_deg, vmat, out);
}

// Round 2
// 488.983 us; speedup vs baseline: 1.1053x; 1.1053x over previous
//
#include <hip/hip_runtime.h>
#include <math.h>

#define N_NODES 50000
#define N_EDGES 800000
#define IN_F 256
#define OUT_F 128
#define RANK 64

typedef unsigned int uint;
typedef unsigned short ushort;

__device__ __forceinline__ ushort f2bf(float x) {
    uint u = __float_as_uint(x);
    uint r = (u + 0x7fffu + ((u >> 16) & 1u)) >> 16;
    return (ushort)r;
}
__device__ __forceinline__ float bf2f(ushort h) {
    return __uint_as_float(((uint)h) << 16);
}
__device__ __forceinline__ float bflo(uint u) { return __uint_as_float(u << 16); }
__device__ __forceinline__ float bfhi(uint u) { return __uint_as_float(u & 0xffff0000u); }

// ---------------- degrees ----------------
__global__ __launch_bounds__(256) void k_degrees(const int* __restrict__ src,
                                                 const int* __restrict__ dst,
                                                 int* __restrict__ out_deg,
                                                 int* __restrict__ in_deg) {
    int i = blockIdx.x * blockDim.x + threadIdx.x;
    if (i < N_EDGES) {
        atomicAdd(&out_deg[src[i]], 1);
        atomicAdd(&in_deg[dst[i]], 1);
    }
}

// ---------------- exclusive scan of in_deg -> row_start (+cursor copy) -----
__global__ __launch_bounds__(1024) void k_scan(const int* __restrict__ in_deg,
                                               int* __restrict__ row_start,
                                               int* __restrict__ cursor) {
    __shared__ int sums[1024];
    const int T = 1024;
    const int per = (N_NODES + T - 1) / T;  // 49
    int tid = threadIdx.x;
    int base = tid * per;

    int local = 0;
    for (int j = 0; j < per; ++j) {
        int idx = base + j;
        if (idx < N_NODES) local += in_deg[idx];
    }
    sums[tid] = local;
    __syncthreads();
    for (int s = 1; s < T; s <<= 1) {
        int v = 0;
        if (tid >= s) v = sums[tid - s];
        __syncthreads();
        if (tid >= s) sums[tid] += v;
        __syncthreads();
    }
    int excl = sums[tid] - local;
    int run = excl;
    for (int j = 0; j < per; ++j) {
        int idx = base + j;
        if (idx < N_NODES) {
            int v = in_deg[idx];
            row_start[idx] = run;
            cursor[idx] = run;
            run += v;
        }
    }
    if (tid == T - 1) row_start[N_NODES] = sums[T - 1];
}

// ---------------- CSR fill ----------------
__global__ __launch_bounds__(256) void k_fill(const int* __restrict__ src,
                                              const int* __restrict__ dst,
                                              int* __restrict__ cursor,
                                              int* __restrict__ csr_src) {
    int i = blockIdx.x * blockDim.x + threadIdx.x;
    if (i < N_EDGES) {
        int p = atomicAdd(&cursor[dst[i]], 1);
        csr_src[p] = src[i];
    }
}

// ---------------- per-node GEMMs -> bf16 outputs ----------------
#define NPB 4
__global__ __launch_bounds__(192) void k_gemm(const float* __restrict__ feat,
                                              const float* __restrict__ w1,
                                              const float* __restrict__ w2,
                                              const int* __restrict__ out_deg,
                                              ushort* __restrict__ feat_sum,
                                              ushort* __restrict__ feat_prod) {
    __shared__ float f[NPB][IN_F];
    __shared__ float scs[NPB];
    int n0 = blockIdx.x * NPB;
    int tid = threadIdx.x;

    if (tid < NPB) {
        int n = n0 + tid;
        float deg = (n < N_NODES) ? (float)out_deg[n] : 1.f;
        scs[tid] = rsqrtf(fmaxf(deg, 1.f));
    }
    __syncthreads();

    for (int idx = tid; idx < NPB * IN_F; idx += 192) {
        int i = idx >> 8;
        int k = idx & (IN_F - 1);
        int n = n0 + i;
        float val = (n < N_NODES) ? feat[(size_t)n * IN_F + k] : 0.f;
        f[i][k] = val * scs[i];
    }
    __syncthreads();

    if (tid < OUT_F) {
        int j = tid;
        float acc[NPB] = {0.f, 0.f, 0.f, 0.f};
#pragma unroll 4
        for (int k = 0; k < IN_F; ++k) {
            float w = w1[k * OUT_F + j];
#pragma unroll
            for (int i = 0; i < NPB; ++i) acc[i] += f[i][k] * w;
        }
#pragma unroll
        for (int i = 0; i < NPB; ++i) {
            int n = n0 + i;
            if (n < N_NODES) feat_sum[(size_t)n * OUT_F + j] = f2bf(acc[i]);
        }
    } else {
        int r = tid - OUT_F;  // 0..63
        float acc[NPB] = {0.f, 0.f, 0.f, 0.f};
#pragma unroll 4
        for (int k = 0; k < IN_F; ++k) {
            float w = w2[k * RANK + r];
#pragma unroll
            for (int i = 0; i < NPB; ++i) acc[i] += f[i][k] * w;
        }
        float b = w2[IN_F * RANK + r];
#pragma unroll
        for (int i = 0; i < NPB; ++i) {
            int n = n0 + i;
            if (n < N_NODES) feat_prod[(size_t)n * RANK + r] = f2bf(tanhf(acc[i] + b));
        }
    }
}

// ---------------- aggregation: one wave per dst node, bf16 gathers, x4 unroll
__global__ __launch_bounds__(256) void k_agg(const ushort* __restrict__ feat_sum,
                                             const ushort* __restrict__ feat_prod,
                                             const int* __restrict__ row_start,
                                             const int* __restrict__ csr_src,
                                             const int* __restrict__ in_deg,
                                             const float* __restrict__ vmat,
                                             float* __restrict__ out) {
    __shared__ float prod_s[4][RANK];
    int wid = threadIdx.x >> 6;
    int lane = threadIdx.x & 63;
    int d = blockIdx.x * 4 + wid;  // grid sized exactly

    int beg = row_start[d];
    int end = row_start[d + 1];

    const uint* fsu = (const uint*)feat_sum;  // row = 64 uints (128 bf16)

    float a0 = 0.f, a1 = 0.f, b0 = 0.f, b1 = 0.f;
    float c0 = 0.f, c1 = 0.f, e0 = 0.f, e1 = 0.f;
    float p0 = 1.f, p1 = 1.f, p2 = 1.f, p3 = 1.f;

    int e = beg;
    for (; e + 4 <= end; e += 4) {
        int sA = csr_src[e + 0];
        int sB = csr_src[e + 1];
        int sC = csr_src[e + 2];
        int sD = csr_src[e + 3];
        uint uA = fsu[(size_t)sA * 64 + lane];
        uint uB = fsu[(size_t)sB * 64 + lane];
        uint uC = fsu[(size_t)sC * 64 + lane];
        uint uD = fsu[(size_t)sD * 64 + lane];
        ushort qA = feat_prod[(size_t)sA * RANK + lane];
        ushort qB = feat_prod[(size_t)sB * RANK + lane];
        ushort qC = feat_prod[(size_t)sC * RANK + lane];
        ushort qD = feat_prod[(size_t)sD * RANK + lane];
        a0 += bflo(uA); a1 += bfhi(uA);
        b0 += bflo(uB); b1 += bfhi(uB);
        c0 += bflo(uC); c1 += bfhi(uC);
        e0 += bflo(uD); e1 += bfhi(uD);
        p0 *= bf2f(qA); p1 *= bf2f(qB);
        p2 *= bf2f(qC); p3 *= bf2f(qD);
    }
    for (; e < end; ++e) {
        int sA = csr_src[e];
        uint uA = fsu[(size_t)sA * 64 + lane];
        ushort qA = feat_prod[(size_t)sA * RANK + lane];
        a0 += bflo(uA); a1 += bfhi(uA);
        p0 *= bf2f(qA);
    }
    float s_lo = (a0 + b0) + (c0 + e0);
    float s_hi = (a1 + b1) + (c1 + e1);
    float pr = (p0 * p1) * (p2 * p3);

    // same-wave LDS broadcast (no barrier needed: slot touched by this wave only)
    prod_s[wid][lane] = pr;

    float o0 = s_lo, o1 = s_hi;
    if (end > beg) {
#pragma unroll 8
        for (int r = 0; r < RANK; ++r) {
            float p = prod_s[wid][r];
            float2 v2 = *(const float2*)(vmat + r * OUT_F + lane * 2);
            o0 += p * v2.x;
            o1 += p * v2.y;
        }
    }
    float sc = rsqrtf(fmaxf((float)in_deg[d], 1.f));
    float2 res;
    res.x = o0 * sc;
    res.y = o1 * sc;
    *(float2*)(out + (size_t)d * OUT_F + lane * 2) = res;
}

extern "C" void kernel_launch(void* const* d_in, const int* in_sizes, int n_in,
                              void* d_out, int out_size, void* d_ws, size_t ws_size,
                              hipStream_t stream) {
    const float* feat = (const float*)d_in[0];
    const float* w1   = (const float*)d_in[1];
    const float* w2   = (const float*)d_in[2];
    const float* vmat = (const float*)d_in[3];
    const int*   src  = (const int*)d_in[4];
    const int*   dst  = (const int*)d_in[5];
    float* out = (float*)d_out;

    char* ws = (char*)d_ws;
    size_t off = 0;
    auto alloc = [&](size_t bytes) {
        void* p = ws + off;
        off = (off + bytes + 255) & ~(size_t)255;
        return p;
    };
    int* out_deg   = (int*)alloc(N_NODES * sizeof(int));
    int* in_deg    = (int*)alloc(N_NODES * sizeof(int));
    int* row_start = (int*)alloc((N_NODES + 1) * sizeof(int));
    int* cursor    = (int*)alloc(N_NODES * sizeof(int));
    int* csr_src   = (int*)alloc(N_EDGES * sizeof(int));
    ushort* feat_sum  = (ushort*)alloc((size_t)N_NODES * OUT_F * sizeof(ushort));
    ushort* feat_prod = (ushort*)alloc((size_t)N_NODES * RANK * sizeof(ushort));

    hipMemsetAsync(out_deg, 0, N_NODES * sizeof(int), stream);
    hipMemsetAsync(in_deg, 0, N_NODES * sizeof(int), stream);

    k_degrees<<<(N_EDGES + 255) / 256, 256, 0, stream>>>(src, dst, out_deg, in_deg);
    k_scan<<<1, 1024, 0, stream>>>(in_deg, row_start, cursor);
    k_fill<<<(N_EDGES + 255) / 256, 256, 0, stream>>>(src, dst, cursor, csr_src);
    k_gemm<<<(N_NODES + NPB - 1) / NPB, 192, 0, stream>>>(feat, w1, w2, out_deg,
                                                          feat_sum, feat_prod);
    k_agg<<<N_NODES / 4, 256, 0, stream>>>(feat_sum, feat_prod, row_start, csr_src,
                                           in_deg, vmat, out);
}

// Round 3
// 391.287 us; speedup vs baseline: 1.3812x; 1.2497x over previous
//
#include <hip/hip_runtime.h>
#include <math.h>

#define N_NODES 50000
#define N_EDGES 800000
#define IN_F 256
#define OUT_F 128
#define RANK 64
#define NCOMB 192  // OUT_F + RANK

typedef unsigned int uint;
typedef unsigned short ushort;
using f32x4 = __attribute__((ext_vector_type(4))) float;
typedef __attribute__((ext_vector_type(8))) short short8;

__device__ __forceinline__ ushort f2bf(float x) {
    uint u = __float_as_uint(x);
    uint r = (u + 0x7fffu + ((u >> 16) & 1u)) >> 16;
    return (ushort)r;
}
__device__ __forceinline__ float bf2f(ushort h) {
    return __uint_as_float(((uint)h) << 16);
}
__device__ __forceinline__ float bflo(uint u) { return __uint_as_float(u << 16); }
__device__ __forceinline__ float bfhi(uint u) { return __uint_as_float(u & 0xffff0000u); }
__device__ __forceinline__ uint pack2(float lo, float hi) {
    return (uint)f2bf(lo) | ((uint)f2bf(hi) << 16);
}

// ---------------- degrees ----------------
__global__ __launch_bounds__(256) void k_degrees(const int* __restrict__ src,
                                                 const int* __restrict__ dst,
                                                 int* __restrict__ out_deg,
                                                 int* __restrict__ in_deg) {
    int i = blockIdx.x * blockDim.x + threadIdx.x;
    if (i < N_EDGES) {
        atomicAdd(&out_deg[src[i]], 1);
        atomicAdd(&in_deg[dst[i]], 1);
    }
}

// ---------------- prep: Bt bf16 [192][256], bias, scale_src ----------------
__global__ __launch_bounds__(256) void k_prep(const float* __restrict__ w1,
                                              const float* __restrict__ w2,
                                              const int* __restrict__ out_deg,
                                              ushort* __restrict__ BtG,
                                              float* __restrict__ bias,
                                              float* __restrict__ scale_src) {
    int i = blockIdx.x * 256 + threadIdx.x;
    if (i < NCOMB * IN_F) {
        int n = i >> 8;       // 0..191 output col
        int k = i & 255;      // 0..255
        float v = (n < OUT_F) ? w1[k * OUT_F + n] : w2[k * RANK + (n - OUT_F)];
        BtG[n * IN_F + k] = f2bf(v);
    }
    if (i < RANK) bias[i] = w2[IN_F * RANK + i];
    if (i < N_NODES) scale_src[i] = rsqrtf(fmaxf((float)out_deg[i], 1.f));
}

// ---------------- exclusive scan of in_deg -> row_start (+cursor copy) -----
__global__ __launch_bounds__(1024) void k_scan(const int* __restrict__ in_deg,
                                               int* __restrict__ row_start,
                                               int* __restrict__ cursor) {
    __shared__ int sums[1024];
    const int T = 1024;
    const int per = (N_NODES + T - 1) / T;
    int tid = threadIdx.x;
    int base = tid * per;

    int local = 0;
    for (int j = 0; j < per; ++j) {
        int idx = base + j;
        if (idx < N_NODES) local += in_deg[idx];
    }
    sums[tid] = local;
    __syncthreads();
    for (int s = 1; s < T; s <<= 1) {
        int v = 0;
        if (tid >= s) v = sums[tid - s];
        __syncthreads();
        if (tid >= s) sums[tid] += v;
        __syncthreads();
    }
    int excl = sums[tid] - local;
    int run = excl;
    for (int j = 0; j < per; ++j) {
        int idx = base + j;
        if (idx < N_NODES) {
            int v = in_deg[idx];
            row_start[idx] = run;
            cursor[idx] = run;
            run += v;
        }
    }
    if (tid == T - 1) row_start[N_NODES] = sums[T - 1];
}

// ---------------- CSR fill ----------------
__global__ __launch_bounds__(256) void k_fill(const int* __restrict__ src,
                                              const int* __restrict__ dst,
                                              int* __restrict__ cursor,
                                              int* __restrict__ csr_src) {
    int i = blockIdx.x * blockDim.x + threadIdx.x;
    if (i < N_EDGES) {
        int p = atomicAdd(&cursor[dst[i]], 1);
        csr_src[p] = src[i];
    }
}

// ---------------- MFMA node GEMM: [N,256]x[256,192] -> bf16 outs ----------
#define BM 64
#define BK 64
__global__ __launch_bounds__(256) void k_gemm_mfma(
    const float* __restrict__ feat,
    const ushort* __restrict__ BtG,      // [192][256] bf16, n-major
    const float* __restrict__ bias,      // [64]
    const float* __restrict__ scale_src, // [N]
    ushort* __restrict__ feat_sum,       // [N][128] bf16
    ushort* __restrict__ feat_prod) {    // [N][64] bf16
    __shared__ __align__(16) ushort A_l[BM * BK];     // 8 KB, XOR-swizzled
    __shared__ __align__(16) ushort B_l[NCOMB * BK];  // 24 KB, XOR-swizzled (n-major rows)
    int tid = threadIdx.x;
    int wid = tid >> 6, lane = tid & 63;
    int n0 = blockIdx.x * BM;

    f32x4 acc[12];
#pragma unroll
    for (int t = 0; t < 12; ++t) acc[t] = (f32x4)(0.f);

    // A staging coords: thread -> (row, 16-float chunk)
    int ar = tid >> 2;
    int ac = (tid & 3) << 4;  // float col: 0,16,32,48
    const float* arow = feat + (size_t)(n0 + ar) * IN_F + ac;
    bool arow_ok = (n0 + ar) < N_NODES;

    for (int kt = 0; kt < IN_F / BK; ++kt) {
        // ---- stage A (64x64 f32 -> bf16, swizzled) ----
        {
            float4 v0, v1, v2, v3;
            if (arow_ok) {
                const float4* p = (const float4*)(arow + kt * BK);
                v0 = p[0]; v1 = p[1]; v2 = p[2]; v3 = p[3];
            } else {
                v0 = v1 = v2 = v3 = make_float4(0.f, 0.f, 0.f, 0.f);
            }
            uint4 w0 = make_uint4(pack2(v0.x, v0.y), pack2(v0.z, v0.w),
                                  pack2(v1.x, v1.y), pack2(v1.z, v1.w));
            uint4 w1q = make_uint4(pack2(v2.x, v2.y), pack2(v2.z, v2.w),
                                   pack2(v3.x, v3.y), pack2(v3.z, v3.w));
            int base = ar * 128 + ac * 2;  // byte offset
            int swz = (ar & 7) << 4;
            *(uint4*)((char*)A_l + (base ^ swz)) = w0;
            *(uint4*)((char*)A_l + ((base + 16) ^ swz)) = w1q;
        }
        // ---- stage B (192 rows x 64 k bf16, swizzled) ----
        {
#pragma unroll
            for (int i = 0; i < 6; ++i) {
                int cc = tid + 256 * i;     // 0..1535 16B-chunks
                int row = cc >> 3;          // 0..191
                int cb = (cc & 7) << 4;     // byte col within 128B row
                uint4 g = *(const uint4*)((const char*)BtG + row * 512 + kt * 128 + cb);
                int b = (row * 128 + cb) ^ ((row & 7) << 4);
                *(uint4*)((char*)B_l + b) = g;
            }
        }
        __syncthreads();
        // ---- MFMA ----
        {
            int arow_f = wid * 16 + (lane & 15);
            int kchunk = lane >> 4;
            int aswz = (arow_f & 7) << 4;
#pragma unroll
            for (int s = 0; s < 2; ++s) {
                int abyte = (arow_f * 128 + s * 64 + kchunk * 16) ^ aswz;
                short8 afrag = *(const short8*)((const char*)A_l + abyte);
#pragma unroll
                for (int t = 0; t < 12; ++t) {
                    int brow = t * 16 + (lane & 15);
                    int bbyte = (brow * 128 + s * 64 + kchunk * 16) ^ ((brow & 7) << 4);
                    short8 bfrag = *(const short8*)((const char*)B_l + bbyte);
                    acc[t] = __builtin_amdgcn_mfma_f32_16x16x32_bf16(afrag, bfrag,
                                                                     acc[t], 0, 0, 0);
                }
            }
        }
        __syncthreads();
    }

    // ---- epilogue: scale (f32), bias+tanh for prod path, bf16 stores ----
    int col = lane & 15;
    int r0 = wid * 16 + ((lane >> 4) << 2);
#pragma unroll
    for (int q = 0; q < 4; ++q) {
        int n = n0 + r0 + q;
        if (n < N_NODES) {
            float s = scale_src[n];
#pragma unroll
            for (int t = 0; t < 8; ++t)
                feat_sum[(size_t)n * OUT_F + t * 16 + col] = f2bf(acc[t][q] * s);
#pragma unroll
            for (int t = 8; t < 12; ++t) {
                float z = acc[t][q] * s + bias[(t - 8) * 16 + col];
                feat_prod[(size_t)n * RANK + (t - 8) * 16 + col] = f2bf(tanhf(z));
            }
        }
    }
}

// ---------------- aggregation: one wave per dst node, bf16 gathers --------
__global__ __launch_bounds__(256) void k_agg(const ushort* __restrict__ feat_sum,
                                             const ushort* __restrict__ feat_prod,
                                             const int* __restrict__ row_start,
                                             const int* __restrict__ csr_src,
                                             const int* __restrict__ in_deg,
                                             const float* __restrict__ vmat,
                                             float* __restrict__ out) {
    __shared__ float prod_s[4][RANK];
    int wid = threadIdx.x >> 6;
    int lane = threadIdx.x & 63;
    int d = blockIdx.x * 4 + wid;

    int beg = row_start[d];
    int end = row_start[d + 1];

    const uint* fsu = (const uint*)feat_sum;

    float a0 = 0.f, a1 = 0.f, b0 = 0.f, b1 = 0.f;
    float c0 = 0.f, c1 = 0.f, e0 = 0.f, e1 = 0.f;
    float p0 = 1.f, p1 = 1.f, p2 = 1.f, p3 = 1.f;

    int e = beg;
    for (; e + 4 <= end; e += 4) {
        int sA = csr_src[e + 0];
        int sB = csr_src[e + 1];
        int sC = csr_src[e + 2];
        int sD = csr_src[e + 3];
        uint uA = fsu[(size_t)sA * 64 + lane];
        uint uB = fsu[(size_t)sB * 64 + lane];
        uint uC = fsu[(size_t)sC * 64 + lane];
        uint uD = fsu[(size_t)sD * 64 + lane];
        ushort qA = feat_prod[(size_t)sA * RANK + lane];
        ushort qB = feat_prod[(size_t)sB * RANK + lane];
        ushort qC = feat_prod[(size_t)sC * RANK + lane];
        ushort qD = feat_prod[(size_t)sD * RANK + lane];
        a0 += bflo(uA); a1 += bfhi(uA);
        b0 += bflo(uB); b1 += bfhi(uB);
        c0 += bflo(uC); c1 += bfhi(uC);
        e0 += bflo(uD); e1 += bfhi(uD);
        p0 *= bf2f(qA); p1 *= bf2f(qB);
        p2 *= bf2f(qC); p3 *= bf2f(qD);
    }
    for (; e < end; ++e) {
        int sA = csr_src[e];
        uint uA = fsu[(size_t)sA * 64 + lane];
        ushort qA = feat_prod[(size_t)sA * RANK + lane];
        a0 += bflo(uA); a1 += bfhi(uA);
        p0 *= bf2f(qA);
    }
    float s_lo = (a0 + b0) + (c0 + e0);
    float s_hi = (a1 + b1) + (c1 + e1);
    float pr = (p0 * p1) * (p2 * p3);

    prod_s[wid][lane] = pr;  // same-wave only: no barrier needed

    float o0 = s_lo, o1 = s_hi;
    if (end > beg) {
#pragma unroll 8
        for (int r = 0; r < RANK; ++r) {
            float p = prod_s[wid][r];
            float2 v2 = *(const float2*)(vmat + r * OUT_F + lane * 2);
            o0 += p * v2.x;
            o1 += p * v2.y;
        }
    }
    float sc = rsqrtf(fmaxf((float)in_deg[d], 1.f));
    float2 res;
    res.x = o0 * sc;
    res.y = o1 * sc;
    *(float2*)(out + (size_t)d * OUT_F + lane * 2) = res;
}

extern "C" void kernel_launch(void* const* d_in, const int* in_sizes, int n_in,
                              void* d_out, int out_size, void* d_ws, size_t ws_size,
                              hipStream_t stream) {
    const float* feat = (const float*)d_in[0];
    const float* w1   = (const float*)d_in[1];
    const float* w2   = (const float*)d_in[2];
    const float* vmat = (const float*)d_in[3];
    const int*   src  = (const int*)d_in[4];
    const int*   dst  = (const int*)d_in[5];
    float* out = (float*)d_out;

    char* ws = (char*)d_ws;
    size_t off = 0;
    auto alloc = [&](size_t bytes) {
        void* p = ws + off;
        off = (off + bytes + 255) & ~(size_t)255;
        return p;
    };
    int* out_deg   = (int*)alloc(N_NODES * sizeof(int));
    int* in_deg    = (int*)alloc(N_NODES * sizeof(int));
    int* row_start = (int*)alloc((N_NODES + 1) * sizeof(int));
    int* cursor    = (int*)alloc(N_NODES * sizeof(int));
    int* csr_src   = (int*)alloc(N_EDGES * sizeof(int));
    ushort* feat_sum  = (ushort*)alloc((size_t)N_NODES * OUT_F * sizeof(ushort));
    ushort* feat_prod = (ushort*)alloc((size_t)N_NODES * RANK * sizeof(ushort));
    ushort* BtG       = (ushort*)alloc((size_t)NCOMB * IN_F * sizeof(ushort));
    float*  bias      = (float*)alloc(RANK * sizeof(float));
    float*  scale_src = (float*)alloc(N_NODES * sizeof(float));

    hipMemsetAsync(out_deg, 0, N_NODES * sizeof(int), stream);
    hipMemsetAsync(in_deg, 0, N_NODES * sizeof(int), stream);

    k_degrees<<<(N_EDGES + 255) / 256, 256, 0, stream>>>(src, dst, out_deg, in_deg);
    k_prep<<<(N_NODES + 255) / 256, 256, 0, stream>>>(w1, w2, out_deg, BtG, bias, scale_src);
    k_scan<<<1, 1024, 0, stream>>>(in_deg, row_start, cursor);
    k_fill<<<(N_EDGES + 255) / 256, 256, 0, stream>>>(src, dst, cursor, csr_src);
    k_gemm_mfma<<<(N_NODES + BM - 1) / BM, 256, 0, stream>>>(feat, BtG, bias, scale_src,
                                                             feat_sum, feat_prod);
    k_agg<<<N_NODES / 4, 256, 0, stream>>>(feat_sum, feat_prod, row_start, csr_src,
                                           in_deg, vmat, out);
}

// Round 4
// 277.693 us; speedup vs baseline: 1.9462x; 1.4091x over previous
//
#include <hip/hip_runtime.h>
#include <math.h>

#define N_NODES 50000
#define N_EDGES 800000
#define IN_F 256
#define OUT_F 128
#define RANK 64
#define NCOMB 192  // OUT_F + RANK
#define NB_SCAN ((N_NODES + 255) / 256)  // 196

typedef unsigned int uint;
typedef unsigned short ushort;
using f32x4 = __attribute__((ext_vector_type(4))) float;
typedef __attribute__((ext_vector_type(8))) short short8;

__device__ __forceinline__ ushort f2bf(float x) {
    uint u = __float_as_uint(x);
    uint r = (u + 0x7fffu + ((u >> 16) & 1u)) >> 16;
    return (ushort)r;
}
__device__ __forceinline__ float bf2f(ushort h) {
    return __uint_as_float(((uint)h) << 16);
}
__device__ __forceinline__ float bflo(uint u) { return __uint_as_float(u << 16); }
__device__ __forceinline__ float bfhi(uint u) { return __uint_as_float(u & 0xffff0000u); }
__device__ __forceinline__ uint pack2(float lo, float hi) {
    return (uint)f2bf(lo) | ((uint)f2bf(hi) << 16);
}

// ---------------- degrees ----------------
__global__ __launch_bounds__(256) void k_degrees(const int* __restrict__ src,
                                                 const int* __restrict__ dst,
                                                 int* __restrict__ out_deg,
                                                 int* __restrict__ in_deg) {
    int i = blockIdx.x * blockDim.x + threadIdx.x;
    if (i < N_EDGES) {
        atomicAdd(&out_deg[src[i]], 1);
        atomicAdd(&in_deg[dst[i]], 1);
    }
}

// ---------------- prep: Bt bf16 [192][256], bias, scale_src ----------------
__global__ __launch_bounds__(256) void k_prep(const float* __restrict__ w1,
                                              const float* __restrict__ w2,
                                              const int* __restrict__ out_deg,
                                              ushort* __restrict__ BtG,
                                              float* __restrict__ bias,
                                              float* __restrict__ scale_src) {
    int i = blockIdx.x * 256 + threadIdx.x;
    if (i < NCOMB * IN_F) {
        int n = i >> 8;
        int k = i & 255;
        float v = (n < OUT_F) ? w1[k * OUT_F + n] : w2[k * RANK + (n - OUT_F)];
        BtG[n * IN_F + k] = f2bf(v);
    }
    if (i < RANK) bias[i] = w2[IN_F * RANK + i];
    if (i < N_NODES) scale_src[i] = rsqrtf(fmaxf((float)out_deg[i], 1.f));
}

// ---------------- device-wide scan, 3 phases ----------------
__global__ __launch_bounds__(256) void k_bsum(const int* __restrict__ in_deg,
                                              int* __restrict__ bsum) {
    __shared__ int red[4];
    int t = threadIdx.x;
    int idx = blockIdx.x * 256 + t;
    int v = (idx < N_NODES) ? in_deg[idx] : 0;
#pragma unroll
    for (int m = 1; m < 64; m <<= 1) v += __shfl_xor(v, m, 64);
    if ((t & 63) == 0) red[t >> 6] = v;
    __syncthreads();
    if (t == 0) bsum[blockIdx.x] = red[0] + red[1] + red[2] + red[3];
}

__global__ __launch_bounds__(256) void k_bscan(const int* __restrict__ bsum,
                                               int* __restrict__ boff,
                                               int* __restrict__ row_last) {
    __shared__ int s[256];
    int t = threadIdx.x;
    int v = (t < NB_SCAN) ? bsum[t] : 0;
    s[t] = v;
    __syncthreads();
    for (int st = 1; st < 256; st <<= 1) {
        int x = 0;
        if (t >= st) x = s[t - st];
        __syncthreads();
        if (t >= st) s[t] += x;
        __syncthreads();
    }
    if (t < NB_SCAN) boff[t] = s[t] - v;
    if (t == 0) *row_last = N_EDGES;  // sum(in_deg) == E always
}

__global__ __launch_bounds__(256) void k_scatter(const int* __restrict__ in_deg,
                                                 const int* __restrict__ boff,
                                                 int* __restrict__ row_start,
                                                 int* __restrict__ cursor) {
    __shared__ int s[256];
    int t = threadIdx.x;
    int idx = blockIdx.x * 256 + t;
    int v = (idx < N_NODES) ? in_deg[idx] : 0;
    s[t] = v;
    __syncthreads();
    for (int st = 1; st < 256; st <<= 1) {
        int x = 0;
        if (t >= st) x = s[t - st];
        __syncthreads();
        if (t >= st) s[t] += x;
        __syncthreads();
    }
    if (idx < N_NODES) {
        int r = boff[blockIdx.x] + s[t] - v;
        row_start[idx] = r;
        cursor[idx] = r;
    }
}

// ---------------- CSR fill ----------------
__global__ __launch_bounds__(256) void k_fill(const int* __restrict__ src,
                                              const int* __restrict__ dst,
                                              int* __restrict__ cursor,
                                              int* __restrict__ csr_src) {
    int i = blockIdx.x * blockDim.x + threadIdx.x;
    if (i < N_EDGES) {
        int p = atomicAdd(&cursor[dst[i]], 1);
        csr_src[p] = src[i];
    }
}

// ---------------- MFMA node GEMM: [N,256]x[256,192] -> bf16 outs ----------
#define BM 64
#define BK 64
__global__ __launch_bounds__(256) void k_gemm_mfma(
    const float* __restrict__ feat,
    const ushort* __restrict__ BtG,
    const float* __restrict__ bias,
    const float* __restrict__ scale_src,
    ushort* __restrict__ feat_sum,
    ushort* __restrict__ feat_prod) {
    __shared__ __align__(16) ushort A_l[BM * BK];
    __shared__ __align__(16) ushort B_l[NCOMB * BK];
    int tid = threadIdx.x;
    int wid = tid >> 6, lane = tid & 63;
    int n0 = blockIdx.x * BM;

    f32x4 acc[12];
#pragma unroll
    for (int t = 0; t < 12; ++t) acc[t] = (f32x4)(0.f);

    int ar = tid >> 2;
    int ac = (tid & 3) << 4;
    const float* arow = feat + (size_t)(n0 + ar) * IN_F + ac;
    bool arow_ok = (n0 + ar) < N_NODES;

    for (int kt = 0; kt < IN_F / BK; ++kt) {
        {
            float4 v0, v1, v2, v3;
            if (arow_ok) {
                const float4* p = (const float4*)(arow + kt * BK);
                v0 = p[0]; v1 = p[1]; v2 = p[2]; v3 = p[3];
            } else {
                v0 = v1 = v2 = v3 = make_float4(0.f, 0.f, 0.f, 0.f);
            }
            uint4 w0 = make_uint4(pack2(v0.x, v0.y), pack2(v0.z, v0.w),
                                  pack2(v1.x, v1.y), pack2(v1.z, v1.w));
            uint4 w1q = make_uint4(pack2(v2.x, v2.y), pack2(v2.z, v2.w),
                                   pack2(v3.x, v3.y), pack2(v3.z, v3.w));
            int base = ar * 128 + ac * 2;
            int swz = (ar & 7) << 4;
            *(uint4*)((char*)A_l + (base ^ swz)) = w0;
            *(uint4*)((char*)A_l + ((base + 16) ^ swz)) = w1q;
        }
        {
#pragma unroll
            for (int i = 0; i < 6; ++i) {
                int cc = tid + 256 * i;
                int row = cc >> 3;
                int cb = (cc & 7) << 4;
                uint4 g = *(const uint4*)((const char*)BtG + row * 512 + kt * 128 + cb);
                int b = (row * 128 + cb) ^ ((row & 7) << 4);
                *(uint4*)((char*)B_l + b) = g;
            }
        }
        __syncthreads();
        {
            int arow_f = wid * 16 + (lane & 15);
            int kchunk = lane >> 4;
            int aswz = (arow_f & 7) << 4;
#pragma unroll
            for (int s = 0; s < 2; ++s) {
                int abyte = (arow_f * 128 + s * 64 + kchunk * 16) ^ aswz;
                short8 afrag = *(const short8*)((const char*)A_l + abyte);
#pragma unroll
                for (int t = 0; t < 12; ++t) {
                    int brow = t * 16 + (lane & 15);
                    int bbyte = (brow * 128 + s * 64 + kchunk * 16) ^ ((brow & 7) << 4);
                    short8 bfrag = *(const short8*)((const char*)B_l + bbyte);
                    acc[t] = __builtin_amdgcn_mfma_f32_16x16x32_bf16(afrag, bfrag,
                                                                     acc[t], 0, 0, 0);
                }
            }
        }
        __syncthreads();
    }

    int col = lane & 15;
    int r0 = wid * 16 + ((lane >> 4) << 2);
#pragma unroll
    for (int q = 0; q < 4; ++q) {
        int n = n0 + r0 + q;
        if (n < N_NODES) {
            float s = scale_src[n];
#pragma unroll
            for (int t = 0; t < 8; ++t)
                feat_sum[(size_t)n * OUT_F + t * 16 + col] = f2bf(acc[t][q] * s);
#pragma unroll
            for (int t = 8; t < 12; ++t) {
                float z = acc[t][q] * s + bias[(t - 8) * 16 + col];
                feat_prod[(size_t)n * RANK + (t - 8) * 16 + col] = f2bf(tanhf(z));
            }
        }
    }
}

// ---------------- aggregation: one wave per dst node, wide gathers --------
// 16-lane group g covers one full row; 4 edges per wave-iter, x2 unrolled.
__global__ __launch_bounds__(256) void k_agg(const ushort* __restrict__ feat_sum,
                                             const ushort* __restrict__ feat_prod,
                                             const int* __restrict__ row_start,
                                             const int* __restrict__ csr_src,
                                             const int* __restrict__ in_deg,
                                             const float* __restrict__ vmat,
                                             float* __restrict__ out) {
    __shared__ float sum_s[4][OUT_F];
    __shared__ float prod_s[4][RANK];
    int wid = threadIdx.x >> 6;
    int lane = threadIdx.x & 63;
    int g = lane >> 4;
    int i = lane & 15;
    int d = blockIdx.x * 4 + wid;

    int beg = row_start[d];
    int end = row_start[d + 1];

    const char* fsb = (const char*)feat_sum;   // row stride 256 B
    const char* fpb = (const char*)feat_prod;  // row stride 128 B

    float acc[8] = {0.f, 0.f, 0.f, 0.f, 0.f, 0.f, 0.f, 0.f};
    float pr[4] = {1.f, 1.f, 1.f, 1.f};

    int e = beg;
    for (; e + 8 <= end; e += 8) {
        int sA = csr_src[e + g];
        int sB = csr_src[e + 4 + g];
        uint4 ua = *(const uint4*)(fsb + (size_t)sA * 256 + i * 16);
        uint4 ub = *(const uint4*)(fsb + (size_t)sB * 256 + i * 16);
        uint2 qa = *(const uint2*)(fpb + (size_t)sA * 128 + i * 8);
        uint2 qb = *(const uint2*)(fpb + (size_t)sB * 128 + i * 8);
        acc[0] += bflo(ua.x); acc[1] += bfhi(ua.x);
        acc[2] += bflo(ua.y); acc[3] += bfhi(ua.y);
        acc[4] += bflo(ua.z); acc[5] += bfhi(ua.z);
        acc[6] += bflo(ua.w); acc[7] += bfhi(ua.w);
        acc[0] += bflo(ub.x); acc[1] += bfhi(ub.x);
        acc[2] += bflo(ub.y); acc[3] += bfhi(ub.y);
        acc[4] += bflo(ub.z); acc[5] += bfhi(ub.z);
        acc[6] += bflo(ub.w); acc[7] += bfhi(ub.w);
        pr[0] *= bflo(qa.x); pr[1] *= bfhi(qa.x);
        pr[2] *= bflo(qa.y); pr[3] *= bfhi(qa.y);
        pr[0] *= bflo(qb.x); pr[1] *= bfhi(qb.x);
        pr[2] *= bflo(qb.y); pr[3] *= bfhi(qb.y);
    }
    for (; e < end; e += 4) {
        if (e + g < end) {
            int sA = csr_src[e + g];
            uint4 ua = *(const uint4*)(fsb + (size_t)sA * 256 + i * 16);
            uint2 qa = *(const uint2*)(fpb + (size_t)sA * 128 + i * 8);
            acc[0] += bflo(ua.x); acc[1] += bfhi(ua.x);
            acc[2] += bflo(ua.y); acc[3] += bfhi(ua.y);
            acc[4] += bflo(ua.z); acc[5] += bfhi(ua.z);
            acc[6] += bflo(ua.w); acc[7] += bfhi(ua.w);
            pr[0] *= bflo(qa.x); pr[1] *= bfhi(qa.x);
            pr[2] *= bflo(qa.y); pr[3] *= bfhi(qa.y);
        }
    }

    // merge the 4 edge-groups: sums add, products multiply (xor 16, 32)
#pragma unroll
    for (int j = 0; j < 8; ++j) {
        acc[j] += __shfl_xor(acc[j], 16, 64);
        acc[j] += __shfl_xor(acc[j], 32, 64);
    }
#pragma unroll
    for (int j = 0; j < 4; ++j) {
        pr[j] *= __shfl_xor(pr[j], 16, 64);
        pr[j] *= __shfl_xor(pr[j], 32, 64);
    }

    // stage to LDS for the float2-store layout (same-wave write/read)
    if (g == 0) {
#pragma unroll
        for (int j = 0; j < 8; ++j) sum_s[wid][i * 8 + j] = acc[j];
#pragma unroll
        for (int j = 0; j < 4; ++j) prod_s[wid][i * 4 + j] = pr[j];
    }

    float o0 = sum_s[wid][lane * 2];
    float o1 = sum_s[wid][lane * 2 + 1];
    if (end > beg) {
#pragma unroll 8
        for (int r = 0; r < RANK; ++r) {
            float p = prod_s[wid][r];
            float2 v2 = *(const float2*)(vmat + r * OUT_F + lane * 2);
            o0 += p * v2.x;
            o1 += p * v2.y;
        }
    }
    float sc = rsqrtf(fmaxf((float)in_deg[d], 1.f));
    float2 res;
    res.x = o0 * sc;
    res.y = o1 * sc;
    *(float2*)(out + (size_t)d * OUT_F + lane * 2) = res;
}

extern "C" void kernel_launch(void* const* d_in, const int* in_sizes, int n_in,
                              void* d_out, int out_size, void* d_ws, size_t ws_size,
                              hipStream_t stream) {
    const float* feat = (const float*)d_in[0];
    const float* w1   = (const float*)d_in[1];
    const float* w2   = (const float*)d_in[2];
    const float* vmat = (const float*)d_in[3];
    const int*   src  = (const int*)d_in[4];
    const int*   dst  = (const int*)d_in[5];
    float* out = (float*)d_out;

    char* ws = (char*)d_ws;
    size_t off = 0;
    auto alloc = [&](size_t bytes) {
        void* p = ws + off;
        off = (off + bytes + 255) & ~(size_t)255;
        return p;
    };
    int* out_deg   = (int*)alloc(N_NODES * sizeof(int));
    int* in_deg    = (int*)alloc(N_NODES * sizeof(int));
    int* row_start = (int*)alloc((N_NODES + 1) * sizeof(int));
    int* cursor    = (int*)alloc(N_NODES * sizeof(int));
    int* csr_src   = (int*)alloc(N_EDGES * sizeof(int));
    int* bsum      = (int*)alloc(NB_SCAN * sizeof(int));
    int* boff      = (int*)alloc(NB_SCAN * sizeof(int));
    ushort* feat_sum  = (ushort*)alloc((size_t)N_NODES * OUT_F * sizeof(ushort));
    ushort* feat_prod = (ushort*)alloc((size_t)N_NODES * RANK * sizeof(ushort));
    ushort* BtG       = (ushort*)alloc((size_t)NCOMB * IN_F * sizeof(ushort));
    float*  bias      = (float*)alloc(RANK * sizeof(float));
    float*  scale_src = (float*)alloc(N_NODES * sizeof(float));

    hipMemsetAsync(out_deg, 0, N_NODES * sizeof(int), stream);
    hipMemsetAsync(in_deg, 0, N_NODES * sizeof(int), stream);

    k_degrees<<<(N_EDGES + 255) / 256, 256, 0, stream>>>(src, dst, out_deg, in_deg);
    k_prep<<<(N_NODES + 255) / 256, 256, 0, stream>>>(w1, w2, out_deg, BtG, bias, scale_src);
    k_bsum<<<NB_SCAN, 256, 0, stream>>>(in_deg, bsum);
    k_bscan<<<1, 256, 0, stream>>>(bsum, boff, row_start + N_NODES);
    k_scatter<<<NB_SCAN, 256, 0, stream>>>(in_deg, boff, row_start, cursor);
    k_fill<<<(N_EDGES + 255) / 256, 256, 0, stream>>>(src, dst, cursor, csr_src);
    k_gemm_mfma<<<(N_NODES + BM - 1) / BM, 256, 0, stream>>>(feat, BtG, bias, scale_src,
                                                             feat_sum, feat_prod);
    k_agg<<<N_NODES / 4, 256, 0, stream>>>(feat_sum, feat_prod, row_start, csr_src,
                                           in_deg, vmat, out);
}

// Round 5
// 274.658 us; speedup vs baseline: 1.9678x; 1.0111x over previous
//
#include <hip/hip_runtime.h>
#include <math.h>

#define N_NODES 50000
#define N_EDGES 800000
#define IN_F 256
#define OUT_F 128
#define RANK 64
#define NCOMB 192  // OUT_F + RANK
#define NB_SCAN ((N_NODES + 255) / 256)  // 196

typedef unsigned int uint;
typedef unsigned short ushort;
using f32x4 = __attribute__((ext_vector_type(4))) float;
typedef __attribute__((ext_vector_type(8))) short short8;

__device__ __forceinline__ ushort f2bf(float x) {
    uint u = __float_as_uint(x);
    uint r = (u + 0x7fffu + ((u >> 16) & 1u)) >> 16;
    return (ushort)r;
}
__device__ __forceinline__ float bflo(uint u) { return __uint_as_float(u << 16); }
__device__ __forceinline__ float bfhi(uint u) { return __uint_as_float(u & 0xffff0000u); }
__device__ __forceinline__ uint pack2(float lo, float hi) {
    return (uint)f2bf(lo) | ((uint)f2bf(hi) << 16);
}

// ---------------- degrees ----------------
__global__ __launch_bounds__(256) void k_degrees(const int* __restrict__ src,
                                                 const int* __restrict__ dst,
                                                 int* __restrict__ out_deg,
                                                 int* __restrict__ in_deg) {
    int i = blockIdx.x * blockDim.x + threadIdx.x;
    if (i < N_EDGES) {
        atomicAdd(&out_deg[src[i]], 1);
        atomicAdd(&in_deg[dst[i]], 1);
    }
}

// ---------------- prep: Bt bf16 [192][256], bias, scale_src ----------------
__global__ __launch_bounds__(256) void k_prep(const float* __restrict__ w1,
                                              const float* __restrict__ w2,
                                              const int* __restrict__ out_deg,
                                              ushort* __restrict__ BtG,
                                              float* __restrict__ bias,
                                              float* __restrict__ scale_src) {
    int i = blockIdx.x * 256 + threadIdx.x;
    if (i < NCOMB * IN_F) {
        int n = i >> 8;
        int k = i & 255;
        float v = (n < OUT_F) ? w1[k * OUT_F + n] : w2[k * RANK + (n - OUT_F)];
        BtG[n * IN_F + k] = f2bf(v);
    }
    if (i < RANK) bias[i] = w2[IN_F * RANK + i];
    if (i < N_NODES) scale_src[i] = rsqrtf(fmaxf((float)out_deg[i], 1.f));
}

// ---------------- device-wide scan, 3 phases ----------------
__global__ __launch_bounds__(256) void k_bsum(const int* __restrict__ in_deg,
                                              int* __restrict__ bsum) {
    __shared__ int red[4];
    int t = threadIdx.x;
    int idx = blockIdx.x * 256 + t;
    int v = (idx < N_NODES) ? in_deg[idx] : 0;
#pragma unroll
    for (int m = 1; m < 64; m <<= 1) v += __shfl_xor(v, m, 64);
    if ((t & 63) == 0) red[t >> 6] = v;
    __syncthreads();
    if (t == 0) bsum[blockIdx.x] = red[0] + red[1] + red[2] + red[3];
}

__global__ __launch_bounds__(256) void k_bscan(const int* __restrict__ bsum,
                                               int* __restrict__ boff,
                                               int* __restrict__ row_last) {
    __shared__ int s[256];
    int t = threadIdx.x;
    int v = (t < NB_SCAN) ? bsum[t] : 0;
    s[t] = v;
    __syncthreads();
    for (int st = 1; st < 256; st <<= 1) {
        int x = 0;
        if (t >= st) x = s[t - st];
        __syncthreads();
        if (t >= st) s[t] += x;
        __syncthreads();
    }
    if (t < NB_SCAN) boff[t] = s[t] - v;
    if (t == 0) *row_last = N_EDGES;  // sum(in_deg) == E always
}

__global__ __launch_bounds__(256) void k_scatter(const int* __restrict__ in_deg,
                                                 const int* __restrict__ boff,
                                                 int* __restrict__ row_start,
                                                 int* __restrict__ cursor) {
    __shared__ int s[256];
    int t = threadIdx.x;
    int idx = blockIdx.x * 256 + t;
    int v = (idx < N_NODES) ? in_deg[idx] : 0;
    s[t] = v;
    __syncthreads();
    for (int st = 1; st < 256; st <<= 1) {
        int x = 0;
        if (t >= st) x = s[t - st];
        __syncthreads();
        if (t >= st) s[t] += x;
        __syncthreads();
    }
    if (idx < N_NODES) {
        int r = boff[blockIdx.x] + s[t] - v;
        row_start[idx] = r;
        cursor[idx] = r;
    }
}

// ---------------- CSR fill ----------------
__global__ __launch_bounds__(256) void k_fill(const int* __restrict__ src,
                                              const int* __restrict__ dst,
                                              int* __restrict__ cursor,
                                              int* __restrict__ csr_src) {
    int i = blockIdx.x * blockDim.x + threadIdx.x;
    if (i < N_EDGES) {
        int p = atomicAdd(&cursor[dst[i]], 1);
        csr_src[p] = src[i];
    }
}

// ---------------- MFMA node GEMM with reg-prefetch (T14) ----------------
#define BM 64
#define BK 64
__global__ __launch_bounds__(256) void k_gemm_mfma(
    const float* __restrict__ feat,
    const ushort* __restrict__ BtG,
    const float* __restrict__ bias,
    const float* __restrict__ scale_src,
    ushort* __restrict__ feat_sum,
    ushort* __restrict__ feat_prod) {
    __shared__ __align__(16) ushort A_l[BM * BK];
    __shared__ __align__(16) ushort B_l[NCOMB * BK];
    int tid = threadIdx.x;
    int wid = tid >> 6, lane = tid & 63;
    int n0 = blockIdx.x * BM;

    f32x4 acc[12];
#pragma unroll
    for (int t = 0; t < 12; ++t) acc[t] = (f32x4)(0.f);

    int ar = tid >> 2;
    int ac = (tid & 3) << 4;
    const float* arow = feat + (size_t)(n0 + ar) * IN_F + ac;
    bool arow_ok = (n0 + ar) < N_NODES;

    float4 v0, v1, v2, v3;
    uint4 bg0, bg1, bg2, bg3, bg4, bg5;

#define LOADA(KT)                                                     \
    do {                                                              \
        if (arow_ok) {                                                \
            const float4* p = (const float4*)(arow + (KT) * BK);      \
            v0 = p[0]; v1 = p[1]; v2 = p[2]; v3 = p[3];               \
        } else {                                                      \
            v0 = v1 = v2 = v3 = make_float4(0.f, 0.f, 0.f, 0.f);     \
        }                                                             \
    } while (0)

#define LOADB1(II, DEST)                                              \
    do {                                                              \
        int cc = tid + 256 * (II);                                    \
        int row = cc >> 3;                                            \
        int cb = (cc & 7) << 4;                                       \
        DEST = *(const uint4*)((const char*)BtG + row * 512 + ktn * 128 + cb); \
    } while (0)

    {
        int ktn = 0;
        LOADA(0);
        LOADB1(0, bg0); LOADB1(1, bg1); LOADB1(2, bg2);
        LOADB1(3, bg3); LOADB1(4, bg4); LOADB1(5, bg5);
    }

    for (int kt = 0; kt < 4; ++kt) {
        // ---- write staged regs to LDS (swizzled) ----
        {
            uint4 w0 = make_uint4(pack2(v0.x, v0.y), pack2(v0.z, v0.w),
                                  pack2(v1.x, v1.y), pack2(v1.z, v1.w));
            uint4 w1q = make_uint4(pack2(v2.x, v2.y), pack2(v2.z, v2.w),
                                   pack2(v3.x, v3.y), pack2(v3.z, v3.w));
            int base = ar * 128 + ac * 2;
            int swz = (ar & 7) << 4;
            *(uint4*)((char*)A_l + (base ^ swz)) = w0;
            *(uint4*)((char*)A_l + ((base + 16) ^ swz)) = w1q;
        }
        {
            uint4 bgs[6] = {bg0, bg1, bg2, bg3, bg4, bg5};
#pragma unroll
            for (int ii = 0; ii < 6; ++ii) {
                int cc = tid + 256 * ii;
                int row = cc >> 3;
                int cb = (cc & 7) << 4;
                int b = (row * 128 + cb) ^ ((row & 7) << 4);
                *(uint4*)((char*)B_l + b) = bgs[ii];
            }
        }
        __syncthreads();
        // ---- prefetch next K-tile into regs (flies under the MFMAs) ----
        if (kt < 3) {
            int ktn = kt + 1;
            LOADA(ktn);
            LOADB1(0, bg0); LOADB1(1, bg1); LOADB1(2, bg2);
            LOADB1(3, bg3); LOADB1(4, bg4); LOADB1(5, bg5);
        }
        // ---- MFMA ----
        {
            int arow_f = wid * 16 + (lane & 15);
            int kchunk = lane >> 4;
            int aswz = (arow_f & 7) << 4;
#pragma unroll
            for (int s = 0; s < 2; ++s) {
                int abyte = (arow_f * 128 + s * 64 + kchunk * 16) ^ aswz;
                short8 afrag = *(const short8*)((const char*)A_l + abyte);
#pragma unroll
                for (int t = 0; t < 12; ++t) {
                    int brow = t * 16 + (lane & 15);
                    int bbyte = (brow * 128 + s * 64 + kchunk * 16) ^ ((brow & 7) << 4);
                    short8 bfrag = *(const short8*)((const char*)B_l + bbyte);
                    acc[t] = __builtin_amdgcn_mfma_f32_16x16x32_bf16(afrag, bfrag,
                                                                     acc[t], 0, 0, 0);
                }
            }
        }
        __syncthreads();
    }

    int col = lane & 15;
    int r0 = wid * 16 + ((lane >> 4) << 2);
#pragma unroll
    for (int q = 0; q < 4; ++q) {
        int n = n0 + r0 + q;
        if (n < N_NODES) {
            float s = scale_src[n];
#pragma unroll
            for (int t = 0; t < 8; ++t)
                feat_sum[(size_t)n * OUT_F + t * 16 + col] = f2bf(acc[t][q] * s);
#pragma unroll
            for (int t = 8; t < 12; ++t) {
                float z = acc[t][q] * s + bias[(t - 8) * 16 + col];
                feat_prod[(size_t)n * RANK + (t - 8) * 16 + col] = f2bf(tanhf(z));
            }
        }
    }
}

// ---------------- aggregation: 16 edges in flight, predicated tail -------
// group g handles edges beg + 16*it + g*4 + {0..3}; 16 lanes cover a row.
__global__ __launch_bounds__(256) void k_agg(const ushort* __restrict__ feat_sum,
                                             const ushort* __restrict__ feat_prod,
                                             const int* __restrict__ row_start,
                                             const int* __restrict__ csr_src,
                                             const int* __restrict__ in_deg,
                                             const float* __restrict__ vmat,
                                             float* __restrict__ out) {
    __shared__ float sum_s[4][OUT_F];
    __shared__ float prod_s[4][RANK];
    int wid = threadIdx.x >> 6;
    int lane = threadIdx.x & 63;
    int g = lane >> 4;
    int i = lane & 15;
    int d = blockIdx.x * 4 + wid;

    int beg = row_start[d];
    int end = row_start[d + 1];
    int deg = end - beg;

    const char* fsb = (const char*)feat_sum;   // row stride 256 B
    const char* fpb = (const char*)feat_prod;  // row stride 128 B

    float a0 = 0.f, a1 = 0.f, a2 = 0.f, a3 = 0.f;
    float a4 = 0.f, a5 = 0.f, a6 = 0.f, a7 = 0.f;
    float p0 = 1.f, p1 = 1.f, p2 = 1.f, p3 = 1.f;

    if (deg > 0) {
        int cl = end - 1;
        int e0 = beg + g * 4;
        int sA = csr_src[min(e0 + 0, cl)];
        int sB = csr_src[min(e0 + 1, cl)];
        int sC = csr_src[min(e0 + 2, cl)];
        int sD = csr_src[min(e0 + 3, cl)];
        int niter = (deg + 15) >> 4;
        for (int it = 0; it < niter; ++it) {
            // gathers for current indices (8 row-loads in flight)
            uint4 uA = *(const uint4*)(fsb + ((size_t)sA << 8) + (i << 4));
            uint4 uB = *(const uint4*)(fsb + ((size_t)sB << 8) + (i << 4));
            uint4 uC = *(const uint4*)(fsb + ((size_t)sC << 8) + (i << 4));
            uint4 uD = *(const uint4*)(fsb + ((size_t)sD << 8) + (i << 4));
            uint2 qA = *(const uint2*)(fpb + ((size_t)sA << 7) + (i << 3));
            uint2 qB = *(const uint2*)(fpb + ((size_t)sB << 7) + (i << 3));
            uint2 qC = *(const uint2*)(fpb + ((size_t)sC << 7) + (i << 3));
            uint2 qD = *(const uint2*)(fpb + ((size_t)sD << 7) + (i << 3));
            // validity of current 4 edges
            bool vA = (e0 + 0) < end;
            bool vB = (e0 + 1) < end;
            bool vC = (e0 + 2) < end;
            bool vD = (e0 + 3) < end;
            float mA = vA ? 1.f : 0.f;
            float mB = vB ? 1.f : 0.f;
            float mC = vC ? 1.f : 0.f;
            float mD = vD ? 1.f : 0.f;
            // prefetch next iteration's indices (clamped; wasted on last iter)
            e0 += 16;
            sA = csr_src[min(e0 + 0, cl)];
            sB = csr_src[min(e0 + 1, cl)];
            sC = csr_src[min(e0 + 2, cl)];
            sD = csr_src[min(e0 + 3, cl)];
            // sums: masked fma (same cost as add)
            a0 = fmaf(mA, bflo(uA.x), a0); a1 = fmaf(mA, bfhi(uA.x), a1);
            a2 = fmaf(mA, bflo(uA.y), a2); a3 = fmaf(mA, bfhi(uA.y), a3);
            a4 = fmaf(mA, bflo(uA.z), a4); a5 = fmaf(mA, bfhi(uA.z), a5);
            a6 = fmaf(mA, bflo(uA.w), a6); a7 = fmaf(mA, bfhi(uA.w), a7);
            a0 = fmaf(mB, bflo(uB.x), a0); a1 = fmaf(mB, bfhi(uB.x), a1);
            a2 = fmaf(mB, bflo(uB.y), a2); a3 = fmaf(mB, bfhi(uB.y), a3);
            a4 = fmaf(mB, bflo(uB.z), a4); a5 = fmaf(mB, bfhi(uB.z), a5);
            a6 = fmaf(mB, bflo(uB.w), a6); a7 = fmaf(mB, bfhi(uB.w), a7);
            a0 = fmaf(mC, bflo(uC.x), a0); a1 = fmaf(mC, bfhi(uC.x), a1);
            a2 = fmaf(mC, bflo(uC.y), a2); a3 = fmaf(mC, bfhi(uC.y), a3);
            a4 = fmaf(mC, bflo(uC.z), a4); a5 = fmaf(mC, bfhi(uC.z), a5);
            a6 = fmaf(mC, bflo(uC.w), a6); a7 = fmaf(mC, bfhi(uC.w), a7);
            a0 = fmaf(mD, bflo(uD.x), a0); a1 = fmaf(mD, bfhi(uD.x), a1);
            a2 = fmaf(mD, bflo(uD.y), a2); a3 = fmaf(mD, bfhi(uD.y), a3);
            a4 = fmaf(mD, bflo(uD.z), a4); a5 = fmaf(mD, bfhi(uD.z), a5);
            a6 = fmaf(mD, bflo(uD.w), a6); a7 = fmaf(mD, bfhi(uD.w), a7);
            // products: masked select to 1.0
            p0 *= vA ? bflo(qA.x) : 1.f; p1 *= vA ? bfhi(qA.x) : 1.f;
            p2 *= vA ? bflo(qA.y) : 1.f; p3 *= vA ? bfhi(qA.y) : 1.f;
            p0 *= vB ? bflo(qB.x) : 1.f; p1 *= vB ? bfhi(qB.x) : 1.f;
            p2 *= vB ? bflo(qB.y) : 1.f; p3 *= vB ? bfhi(qB.y) : 1.f;
            p0 *= vC ? bflo(qC.x) : 1.f; p1 *= vC ? bfhi(qC.x) : 1.f;
            p2 *= vC ? bflo(qC.y) : 1.f; p3 *= vC ? bfhi(qC.y) : 1.f;
            p0 *= vD ? bflo(qD.x) : 1.f; p1 *= vD ? bfhi(qD.x) : 1.f;
            p2 *= vD ? bflo(qD.y) : 1.f; p3 *= vD ? bfhi(qD.y) : 1.f;
        }
    }

    // merge the 4 edge-groups: sums add, products multiply (xor 16, 32)
    a0 += __shfl_xor(a0, 16, 64); a0 += __shfl_xor(a0, 32, 64);
    a1 += __shfl_xor(a1, 16, 64); a1 += __shfl_xor(a1, 32, 64);
    a2 += __shfl_xor(a2, 16, 64); a2 += __shfl_xor(a2, 32, 64);
    a3 += __shfl_xor(a3, 16, 64); a3 += __shfl_xor(a3, 32, 64);
    a4 += __shfl_xor(a4, 16, 64); a4 += __shfl_xor(a4, 32, 64);
    a5 += __shfl_xor(a5, 16, 64); a5 += __shfl_xor(a5, 32, 64);
    a6 += __shfl_xor(a6, 16, 64); a6 += __shfl_xor(a6, 32, 64);
    a7 += __shfl_xor(a7, 16, 64); a7 += __shfl_xor(a7, 32, 64);
    p0 *= __shfl_xor(p0, 16, 64); p0 *= __shfl_xor(p0, 32, 64);
    p1 *= __shfl_xor(p1, 16, 64); p1 *= __shfl_xor(p1, 32, 64);
    p2 *= __shfl_xor(p2, 16, 64); p2 *= __shfl_xor(p2, 32, 64);
    p3 *= __shfl_xor(p3, 16, 64); p3 *= __shfl_xor(p3, 32, 64);

    // stage to LDS for the float2-store layout (same-wave write/read)
    if (g == 0) {
        sum_s[wid][i * 8 + 0] = a0; sum_s[wid][i * 8 + 1] = a1;
        sum_s[wid][i * 8 + 2] = a2; sum_s[wid][i * 8 + 3] = a3;
        sum_s[wid][i * 8 + 4] = a4; sum_s[wid][i * 8 + 5] = a5;
        sum_s[wid][i * 8 + 6] = a6; sum_s[wid][i * 8 + 7] = a7;
        prod_s[wid][i * 4 + 0] = p0; prod_s[wid][i * 4 + 1] = p1;
        prod_s[wid][i * 4 + 2] = p2; prod_s[wid][i * 4 + 3] = p3;
    }

    float o0 = sum_s[wid][lane * 2];
    float o1 = sum_s[wid][lane * 2 + 1];
    if (deg > 0) {
#pragma unroll 8
        for (int r = 0; r < RANK; ++r) {
            float p = prod_s[wid][r];
            float2 v2 = *(const float2*)(vmat + r * OUT_F + lane * 2);
            o0 += p * v2.x;
            o1 += p * v2.y;
        }
    }
    float sc = rsqrtf(fmaxf((float)in_deg[d], 1.f));
    float2 res;
    res.x = o0 * sc;
    res.y = o1 * sc;
    *(float2*)(out + (size_t)d * OUT_F + lane * 2) = res;
}

extern "C" void kernel_launch(void* const* d_in, const int* in_sizes, int n_in,
                              void* d_out, int out_size, void* d_ws, size_t ws_size,
                              hipStream_t stream) {
    const float* feat = (const float*)d_in[0];
    const float* w1   = (const float*)d_in[1];
    const float* w2   = (const float*)d_in[2];
    const float* vmat = (const float*)d_in[3];
    const int*   src  = (const int*)d_in[4];
    const int*   dst  = (const int*)d_in[5];
    float* out = (float*)d_out;

    char* ws = (char*)d_ws;
    size_t off = 0;
    auto alloc = [&](size_t bytes) {
        void* p = ws + off;
        off = (off + bytes + 255) & ~(size_t)255;
        return p;
    };
    int* degs      = (int*)alloc(2 * N_NODES * sizeof(int));  // out_deg | in_deg
    int* out_deg   = degs;
    int* in_deg    = degs + N_NODES;
    int* row_start = (int*)alloc((N_NODES + 1) * sizeof(int));
    int* cursor    = (int*)alloc(N_NODES * sizeof(int));
    int* csr_src   = (int*)alloc(N_EDGES * sizeof(int));
    int* bsum      = (int*)alloc(NB_SCAN * sizeof(int));
    int* boff      = (int*)alloc(NB_SCAN * sizeof(int));
    ushort* feat_sum  = (ushort*)alloc((size_t)N_NODES * OUT_F * sizeof(ushort));
    ushort* feat_prod = (ushort*)alloc((size_t)N_NODES * RANK * sizeof(ushort));
    ushort* BtG       = (ushort*)alloc((size_t)NCOMB * IN_F * sizeof(ushort));
    float*  bias      = (float*)alloc(RANK * sizeof(float));
    float*  scale_src = (float*)alloc(N_NODES * sizeof(float));

    hipMemsetAsync(degs, 0, 2 * N_NODES * sizeof(int), stream);

    k_degrees<<<(N_EDGES + 255) / 256, 256, 0, stream>>>(src, dst, out_deg, in_deg);
    k_prep<<<(N_NODES + 255) / 256, 256, 0, stream>>>(w1, w2, out_deg, BtG, bias, scale_src);
    k_bsum<<<NB_SCAN, 256, 0, stream>>>(in_deg, bsum);
    k_bscan<<<1, 256, 0, stream>>>(bsum, boff, row_start + N_NODES);
    k_scatter<<<NB_SCAN, 256, 0, stream>>>(in_deg, boff, row_start, cursor);
    k_fill<<<(N_EDGES + 255) / 256, 256, 0, stream>>>(src, dst, cursor, csr_src);
    k_gemm_mfma<<<(N_NODES + BM - 1) / BM, 256, 0, stream>>>(feat, BtG, bias, scale_src,
                                                             feat_sum, feat_prod);
    k_agg<<<N_NODES / 4, 256, 0, stream>>>(feat_sum, feat_prod, row_start, csr_src,
                                           in_deg, vmat, out);
}

// Round 6
// 272.056 us; speedup vs baseline: 1.9866x; 1.0096x over previous
//
#include <hip/hip_runtime.h>
#include <math.h>

#define N_NODES 50000
#define N_EDGES 800000
#define IN_F 256
#define OUT_F 128
#define RANK 64
#define NCOMB 192  // OUT_F + RANK
#define REC 192    // ushorts per node record (128 sum + 64 prod) = 384 B
#define NB_SCAN ((N_NODES + 255) / 256)  // 196

typedef unsigned int uint;
typedef unsigned short ushort;
using f32x4 = __attribute__((ext_vector_type(4))) float;
typedef __attribute__((ext_vector_type(8))) short short8;

__device__ __forceinline__ ushort f2bf(float x) {
    uint u = __float_as_uint(x);
    uint r = (u + 0x7fffu + ((u >> 16) & 1u)) >> 16;
    return (ushort)r;
}
__device__ __forceinline__ float bflo(uint u) { return __uint_as_float(u << 16); }
__device__ __forceinline__ float bfhi(uint u) { return __uint_as_float(u & 0xffff0000u); }
__device__ __forceinline__ uint pack2(float lo, float hi) {
    return (uint)f2bf(lo) | ((uint)f2bf(hi) << 16);
}

// ---------------- degrees ----------------
__global__ __launch_bounds__(256) void k_degrees(const int* __restrict__ src,
                                                 const int* __restrict__ dst,
                                                 int* __restrict__ out_deg,
                                                 int* __restrict__ in_deg) {
    int i = blockIdx.x * blockDim.x + threadIdx.x;
    if (i < N_EDGES) {
        atomicAdd(&out_deg[src[i]], 1);
        atomicAdd(&in_deg[dst[i]], 1);
    }
}

// ---------------- prep: Bt bf16 [192][256], bias (no degree dependency) ----
__global__ __launch_bounds__(256) void k_prep(const float* __restrict__ w1,
                                              const float* __restrict__ w2,
                                              ushort* __restrict__ BtG,
                                              float* __restrict__ bias) {
    int i = blockIdx.x * 256 + threadIdx.x;
    if (i < NCOMB * IN_F) {
        int n = i >> 8;
        int k = i & 255;
        float v = (n < OUT_F) ? w1[k * OUT_F + n] : w2[k * RANK + (n - OUT_F)];
        BtG[n * IN_F + k] = f2bf(v);
    }
    if (i < RANK) bias[i] = w2[IN_F * RANK + i];
}

// ---------------- device-wide scan, 3 phases ----------------
__global__ __launch_bounds__(256) void k_bsum(const int* __restrict__ in_deg,
                                              int* __restrict__ bsum) {
    __shared__ int red[4];
    int t = threadIdx.x;
    int idx = blockIdx.x * 256 + t;
    int v = (idx < N_NODES) ? in_deg[idx] : 0;
#pragma unroll
    for (int m = 1; m < 64; m <<= 1) v += __shfl_xor(v, m, 64);
    if ((t & 63) == 0) red[t >> 6] = v;
    __syncthreads();
    if (t == 0) bsum[blockIdx.x] = red[0] + red[1] + red[2] + red[3];
}

__global__ __launch_bounds__(256) void k_bscan(const int* __restrict__ bsum,
                                               int* __restrict__ boff,
                                               int* __restrict__ row_last) {
    __shared__ int s[256];
    int t = threadIdx.x;
    int v = (t < NB_SCAN) ? bsum[t] : 0;
    s[t] = v;
    __syncthreads();
    for (int st = 1; st < 256; st <<= 1) {
        int x = 0;
        if (t >= st) x = s[t - st];
        __syncthreads();
        if (t >= st) s[t] += x;
        __syncthreads();
    }
    if (t < NB_SCAN) boff[t] = s[t] - v;
    if (t == 0) *row_last = N_EDGES;  // sum(in_deg) == E always
}

__global__ __launch_bounds__(256) void k_scatter(const int* __restrict__ in_deg,
                                                 const int* __restrict__ boff,
                                                 int* __restrict__ row_start,
                                                 int* __restrict__ cursor) {
    __shared__ int s[256];
    int t = threadIdx.x;
    int idx = blockIdx.x * 256 + t;
    int v = (idx < N_NODES) ? in_deg[idx] : 0;
    s[t] = v;
    __syncthreads();
    for (int st = 1; st < 256; st <<= 1) {
        int x = 0;
        if (t >= st) x = s[t - st];
        __syncthreads();
        if (t >= st) s[t] += x;
        __syncthreads();
    }
    if (idx < N_NODES) {
        int r = boff[blockIdx.x] + s[t] - v;
        row_start[idx] = r;
        cursor[idx] = r;
    }
}

// ---------------- CSR fill ----------------
__global__ __launch_bounds__(256) void k_fill(const int* __restrict__ src,
                                              const int* __restrict__ dst,
                                              int* __restrict__ cursor,
                                              int* __restrict__ csr_src) {
    int i = blockIdx.x * blockDim.x + threadIdx.x;
    if (i < N_EDGES) {
        int p = atomicAdd(&cursor[dst[i]], 1);
        csr_src[p] = src[i];
    }
}

// ---------------- MFMA node GEMM with reg-prefetch -> unified record -------
#define BM 64
#define BK 64
__global__ __launch_bounds__(256) void k_gemm_mfma(
    const float* __restrict__ feat,
    const ushort* __restrict__ BtG,
    const float* __restrict__ bias,
    const int* __restrict__ out_deg,
    ushort* __restrict__ feat_rec) {  // [N][192]: 128 sum-bf16 | 64 prod-bf16
    __shared__ __align__(16) ushort A_l[BM * BK];
    __shared__ __align__(16) ushort B_l[NCOMB * BK];
    int tid = threadIdx.x;
    int wid = tid >> 6, lane = tid & 63;
    int n0 = blockIdx.x * BM;

    f32x4 acc[12];
#pragma unroll
    for (int t = 0; t < 12; ++t) acc[t] = (f32x4)(0.f);

    int ar = tid >> 2;
    int ac = (tid & 3) << 4;
    const float* arow = feat + (size_t)(n0 + ar) * IN_F + ac;
    bool arow_ok = (n0 + ar) < N_NODES;

    float4 v0, v1, v2, v3;
    uint4 bg0, bg1, bg2, bg3, bg4, bg5;

#define LOADA(KT)                                                     \
    do {                                                              \
        if (arow_ok) {                                                \
            const float4* p = (const float4*)(arow + (KT) * BK);      \
            v0 = p[0]; v1 = p[1]; v2 = p[2]; v3 = p[3];               \
        } else {                                                      \
            v0 = v1 = v2 = v3 = make_float4(0.f, 0.f, 0.f, 0.f);     \
        }                                                             \
    } while (0)

#define LOADB1(II, DEST)                                              \
    do {                                                              \
        int cc = tid + 256 * (II);                                    \
        int row = cc >> 3;                                            \
        int cb = (cc & 7) << 4;                                       \
        DEST = *(const uint4*)((const char*)BtG + row * 512 + ktn * 128 + cb); \
    } while (0)

    {
        int ktn = 0;
        LOADA(0);
        LOADB1(0, bg0); LOADB1(1, bg1); LOADB1(2, bg2);
        LOADB1(3, bg3); LOADB1(4, bg4); LOADB1(5, bg5);
    }

    for (int kt = 0; kt < 4; ++kt) {
        {
            uint4 w0 = make_uint4(pack2(v0.x, v0.y), pack2(v0.z, v0.w),
                                  pack2(v1.x, v1.y), pack2(v1.z, v1.w));
            uint4 w1q = make_uint4(pack2(v2.x, v2.y), pack2(v2.z, v2.w),
                                   pack2(v3.x, v3.y), pack2(v3.z, v3.w));
            int base = ar * 128 + ac * 2;
            int swz = (ar & 7) << 4;
            *(uint4*)((char*)A_l + (base ^ swz)) = w0;
            *(uint4*)((char*)A_l + ((base + 16) ^ swz)) = w1q;
        }
        {
            uint4 bgs[6] = {bg0, bg1, bg2, bg3, bg4, bg5};
#pragma unroll
            for (int ii = 0; ii < 6; ++ii) {
                int cc = tid + 256 * ii;
                int row = cc >> 3;
                int cb = (cc & 7) << 4;
                int b = (row * 128 + cb) ^ ((row & 7) << 4);
                *(uint4*)((char*)B_l + b) = bgs[ii];
            }
        }
        __syncthreads();
        if (kt < 3) {
            int ktn = kt + 1;
            LOADA(ktn);
            LOADB1(0, bg0); LOADB1(1, bg1); LOADB1(2, bg2);
            LOADB1(3, bg3); LOADB1(4, bg4); LOADB1(5, bg5);
        }
        {
            int arow_f = wid * 16 + (lane & 15);
            int kchunk = lane >> 4;
            int aswz = (arow_f & 7) << 4;
#pragma unroll
            for (int s = 0; s < 2; ++s) {
                int abyte = (arow_f * 128 + s * 64 + kchunk * 16) ^ aswz;
                short8 afrag = *(const short8*)((const char*)A_l + abyte);
#pragma unroll
                for (int t = 0; t < 12; ++t) {
                    int brow = t * 16 + (lane & 15);
                    int bbyte = (brow * 128 + s * 64 + kchunk * 16) ^ ((brow & 7) << 4);
                    short8 bfrag = *(const short8*)((const char*)B_l + bbyte);
                    acc[t] = __builtin_amdgcn_mfma_f32_16x16x32_bf16(afrag, bfrag,
                                                                     acc[t], 0, 0, 0);
                }
            }
        }
        __syncthreads();
    }

    int col = lane & 15;
    int r0 = wid * 16 + ((lane >> 4) << 2);
#pragma unroll
    for (int q = 0; q < 4; ++q) {
        int n = n0 + r0 + q;
        if (n < N_NODES) {
            float s = rsqrtf(fmaxf((float)out_deg[n], 1.f));
            ushort* rec = feat_rec + (size_t)n * REC;
#pragma unroll
            for (int t = 0; t < 8; ++t)
                rec[t * 16 + col] = f2bf(acc[t][q] * s);
#pragma unroll
            for (int t = 8; t < 12; ++t) {
                float z = acc[t][q] * s + bias[(t - 8) * 16 + col];
                rec[OUT_F + (t - 8) * 16 + col] = f2bf(tanhf(z));
            }
        }
    }
}

// ---------------- aggregation: unified 384-B record gather ----------------
// group g handles edges beg + 16*it + g*4 + {0..3}; 16 lanes cover a record.
__global__ __launch_bounds__(256) void k_agg(const ushort* __restrict__ feat_rec,
                                             const int* __restrict__ row_start,
                                             const int* __restrict__ csr_src,
                                             const int* __restrict__ in_deg,
                                             const float* __restrict__ vmat,
                                             float* __restrict__ out) {
    __shared__ float sum_s[4][OUT_F];
    __shared__ float prod_s[4][RANK];
    int wid = threadIdx.x >> 6;
    int lane = threadIdx.x & 63;
    int g = lane >> 4;
    int i = lane & 15;
    int d = blockIdx.x * 4 + wid;

    int beg = row_start[d];
    int end = row_start[d + 1];
    int deg = end - beg;

    const char* frb = (const char*)feat_rec;  // record stride 384 B

    float a0 = 0.f, a1 = 0.f, a2 = 0.f, a3 = 0.f;
    float a4 = 0.f, a5 = 0.f, a6 = 0.f, a7 = 0.f;
    float p0 = 1.f, p1 = 1.f, p2 = 1.f, p3 = 1.f;

    if (deg > 0) {
        int cl = end - 1;
        int e0 = beg + g * 4;
        int sA = csr_src[min(e0 + 0, cl)];
        int sB = csr_src[min(e0 + 1, cl)];
        int sC = csr_src[min(e0 + 2, cl)];
        int sD = csr_src[min(e0 + 3, cl)];
        int niter = (deg + 15) >> 4;
        for (int it = 0; it < niter; ++it) {
            size_t bA = (size_t)sA * 384, bB = (size_t)sB * 384;
            size_t bC = (size_t)sC * 384, bD = (size_t)sD * 384;
            uint4 uA = *(const uint4*)(frb + bA + (i << 4));
            uint4 uB = *(const uint4*)(frb + bB + (i << 4));
            uint4 uC = *(const uint4*)(frb + bC + (i << 4));
            uint4 uD = *(const uint4*)(frb + bD + (i << 4));
            uint2 qA = *(const uint2*)(frb + bA + 256 + (i << 3));
            uint2 qB = *(const uint2*)(frb + bB + 256 + (i << 3));
            uint2 qC = *(const uint2*)(frb + bC + 256 + (i << 3));
            uint2 qD = *(const uint2*)(frb + bD + 256 + (i << 3));
            bool vA = (e0 + 0) < end;
            bool vB = (e0 + 1) < end;
            bool vC = (e0 + 2) < end;
            bool vD = (e0 + 3) < end;
            float mA = vA ? 1.f : 0.f;
            float mB = vB ? 1.f : 0.f;
            float mC = vC ? 1.f : 0.f;
            float mD = vD ? 1.f : 0.f;
            e0 += 16;
            sA = csr_src[min(e0 + 0, cl)];
            sB = csr_src[min(e0 + 1, cl)];
            sC = csr_src[min(e0 + 2, cl)];
            sD = csr_src[min(e0 + 3, cl)];
            a0 = fmaf(mA, bflo(uA.x), a0); a1 = fmaf(mA, bfhi(uA.x), a1);
            a2 = fmaf(mA, bflo(uA.y), a2); a3 = fmaf(mA, bfhi(uA.y), a3);
            a4 = fmaf(mA, bflo(uA.z), a4); a5 = fmaf(mA, bfhi(uA.z), a5);
            a6 = fmaf(mA, bflo(uA.w), a6); a7 = fmaf(mA, bfhi(uA.w), a7);
            a0 = fmaf(mB, bflo(uB.x), a0); a1 = fmaf(mB, bfhi(uB.x), a1);
            a2 = fmaf(mB, bflo(uB.y), a2); a3 = fmaf(mB, bfhi(uB.y), a3);
            a4 = fmaf(mB, bflo(uB.z), a4); a5 = fmaf(mB, bfhi(uB.z), a5);
            a6 = fmaf(mB, bflo(uB.w), a6); a7 = fmaf(mB, bfhi(uB.w), a7);
            a0 = fmaf(mC, bflo(uC.x), a0); a1 = fmaf(mC, bfhi(uC.x), a1);
            a2 = fmaf(mC, bflo(uC.y), a2); a3 = fmaf(mC, bfhi(uC.y), a3);
            a4 = fmaf(mC, bflo(uC.z), a4); a5 = fmaf(mC, bfhi(uC.z), a5);
            a6 = fmaf(mC, bflo(uC.w), a6); a7 = fmaf(mC, bfhi(uC.w), a7);
            a0 = fmaf(mD, bflo(uD.x), a0); a1 = fmaf(mD, bfhi(uD.x), a1);
            a2 = fmaf(mD, bflo(uD.y), a2); a3 = fmaf(mD, bfhi(uD.y), a3);
            a4 = fmaf(mD, bflo(uD.z), a4); a5 = fmaf(mD, bfhi(uD.z), a5);
            a6 = fmaf(mD, bflo(uD.w), a6); a7 = fmaf(mD, bfhi(uD.w), a7);
            p0 *= vA ? bflo(qA.x) : 1.f; p1 *= vA ? bfhi(qA.x) : 1.f;
            p2 *= vA ? bflo(qA.y) : 1.f; p3 *= vA ? bfhi(qA.y) : 1.f;
            p0 *= vB ? bflo(qB.x) : 1.f; p1 *= vB ? bfhi(qB.x) : 1.f;
            p2 *= vB ? bflo(qB.y) : 1.f; p3 *= vB ? bfhi(qB.y) : 1.f;
            p0 *= vC ? bflo(qC.x) : 1.f; p1 *= vC ? bfhi(qC.x) : 1.f;
            p2 *= vC ? bflo(qC.y) : 1.f; p3 *= vC ? bfhi(qC.y) : 1.f;
            p0 *= vD ? bflo(qD.x) : 1.f; p1 *= vD ? bfhi(qD.x) : 1.f;
            p2 *= vD ? bflo(qD.y) : 1.f; p3 *= vD ? bfhi(qD.y) : 1.f;
        }
    }

    a0 += __shfl_xor(a0, 16, 64); a0 += __shfl_xor(a0, 32, 64);
    a1 += __shfl_xor(a1, 16, 64); a1 += __shfl_xor(a1, 32, 64);
    a2 += __shfl_xor(a2, 16, 64); a2 += __shfl_xor(a2, 32, 64);
    a3 += __shfl_xor(a3, 16, 64); a3 += __shfl_xor(a3, 32, 64);
    a4 += __shfl_xor(a4, 16, 64); a4 += __shfl_xor(a4, 32, 64);
    a5 += __shfl_xor(a5, 16, 64); a5 += __shfl_xor(a5, 32, 64);
    a6 += __shfl_xor(a6, 16, 64); a6 += __shfl_xor(a6, 32, 64);
    a7 += __shfl_xor(a7, 16, 64); a7 += __shfl_xor(a7, 32, 64);
    p0 *= __shfl_xor(p0, 16, 64); p0 *= __shfl_xor(p0, 32, 64);
    p1 *= __shfl_xor(p1, 16, 64); p1 *= __shfl_xor(p1, 32, 64);
    p2 *= __shfl_xor(p2, 16, 64); p2 *= __shfl_xor(p2, 32, 64);
    p3 *= __shfl_xor(p3, 16, 64); p3 *= __shfl_xor(p3, 32, 64);

    if (g == 0) {
        sum_s[wid][i * 8 + 0] = a0; sum_s[wid][i * 8 + 1] = a1;
        sum_s[wid][i * 8 + 2] = a2; sum_s[wid][i * 8 + 3] = a3;
        sum_s[wid][i * 8 + 4] = a4; sum_s[wid][i * 8 + 5] = a5;
        sum_s[wid][i * 8 + 6] = a6; sum_s[wid][i * 8 + 7] = a7;
        prod_s[wid][i * 4 + 0] = p0; prod_s[wid][i * 4 + 1] = p1;
        prod_s[wid][i * 4 + 2] = p2; prod_s[wid][i * 4 + 3] = p3;
    }

    float o0 = sum_s[wid][lane * 2];
    float o1 = sum_s[wid][lane * 2 + 1];
    if (deg > 0) {
#pragma unroll 8
        for (int r = 0; r < RANK; ++r) {
            float p = prod_s[wid][r];
            float2 v2 = *(const float2*)(vmat + r * OUT_F + lane * 2);
            o0 += p * v2.x;
            o1 += p * v2.y;
        }
    }
    float sc = rsqrtf(fmaxf((float)in_deg[d], 1.f));
    float2 res;
    res.x = o0 * sc;
    res.y = o1 * sc;
    *(float2*)(out + (size_t)d * OUT_F + lane * 2) = res;
}

extern "C" void kernel_launch(void* const* d_in, const int* in_sizes, int n_in,
                              void* d_out, int out_size, void* d_ws, size_t ws_size,
                              hipStream_t stream) {
    const float* feat = (const float*)d_in[0];
    const float* w1   = (const float*)d_in[1];
    const float* w2   = (const float*)d_in[2];
    const float* vmat = (const float*)d_in[3];
    const int*   src  = (const int*)d_in[4];
    const int*   dst  = (const int*)d_in[5];
    float* out = (float*)d_out;

    char* ws = (char*)d_ws;
    size_t off = 0;
    auto alloc = [&](size_t bytes) {
        void* p = ws + off;
        off = (off + bytes + 255) & ~(size_t)255;
        return p;
    };
    int* degs      = (int*)alloc(2 * N_NODES * sizeof(int));  // out_deg | in_deg
    int* out_deg   = degs;
    int* in_deg    = degs + N_NODES;
    int* row_start = (int*)alloc((N_NODES + 1) * sizeof(int));
    int* cursor    = (int*)alloc(N_NODES * sizeof(int));
    int* csr_src   = (int*)alloc(N_EDGES * sizeof(int));
    int* bsum      = (int*)alloc(NB_SCAN * sizeof(int));
    int* boff      = (int*)alloc(NB_SCAN * sizeof(int));
    ushort* feat_rec = (ushort*)alloc((size_t)N_NODES * REC * sizeof(ushort));
    ushort* BtG      = (ushort*)alloc((size_t)NCOMB * IN_F * sizeof(ushort));
    float*  bias     = (float*)alloc(RANK * sizeof(float));

    hipMemsetAsync(degs, 0, 2 * N_NODES * sizeof(int), stream);

    k_prep<<<(NCOMB * IN_F + 255) / 256, 256, 0, stream>>>(w1, w2, BtG, bias);
    k_degrees<<<(N_EDGES + 255) / 256, 256, 0, stream>>>(src, dst, out_deg, in_deg);
    k_bsum<<<NB_SCAN, 256, 0, stream>>>(in_deg, bsum);
    k_bscan<<<1, 256, 0, stream>>>(bsum, boff, row_start + N_NODES);
    k_scatter<<<NB_SCAN, 256, 0, stream>>>(in_deg, boff, row_start, cursor);
    k_fill<<<(N_EDGES + 255) / 256, 256, 0, stream>>>(src, dst, cursor, csr_src);
    k_gemm_mfma<<<(N_NODES + BM - 1) / BM, 256, 0, stream>>>(feat, BtG, bias, out_deg,
                                                             feat_rec);
    k_agg<<<N_NODES / 4, 256, 0, stream>>>(feat_rec, row_start, csr_src,
                                           in_deg, vmat, out);
}